// Round 1
// baseline (238.429 us; speedup 1.0000x reference)
//
#include <hip/hip_runtime.h>

// MaxPool2d: X (16, 64, 512, 512) f32, kernel=2, stride=2, VALID
// -> out (16, 64, 256, 256) f32.
// Pure streaming op: each input elem used exactly once. Memory-bound.
// One thread = 2 adjacent output pixels = one float4 from each of the
// 2 input rows (perfectly coalesced 16B/lane), float2 store.

__global__ __launch_bounds__(256) void SvegaMaxPool2x2_kernel(
    const float4* __restrict__ X4,   // input viewed as float4
    float2* __restrict__ Y2,         // output viewed as float2
    int nthreads)                    // total output-pairs
{
    int t = blockIdx.x * blockDim.x + threadIdx.x;
    if (t >= nthreads) return;

    // Each plane: input 512x512 (= 65536 float4), output 256x256 (= 32768 pairs)
    int plane = t >> 15;          // / 32768 pairs per plane
    int p     = t & 32767;
    int oh    = p >> 7;           // output row (128 pairs per output row)
    int pw    = p & 127;          // pair index within row

    // input float4 index: plane*65536 + (oh*2)*128 + pw
    long base = ((long)plane << 16) + (oh << 8) + pw;

    float4 r0 = X4[base];         // input row 2*oh,   cols 4*pw .. 4*pw+3
    float4 r1 = X4[base + 128];   // input row 2*oh+1, same cols

    float2 out;
    out.x = fmaxf(fmaxf(r0.x, r0.y), fmaxf(r1.x, r1.y));
    out.y = fmaxf(fmaxf(r0.z, r0.w), fmaxf(r1.z, r1.w));

    Y2[t] = out;
}

extern "C" void kernel_launch(void* const* d_in, const int* in_sizes, int n_in,
                              void* d_out, int out_size, void* d_ws, size_t ws_size,
                              hipStream_t stream) {
    const float4* X4 = (const float4*)d_in[0];
    float2* Y2 = (float2*)d_out;

    int nthreads = out_size / 2;               // 67,108,864 / 2 = 33,554,432
    int blocks = (nthreads + 255) / 256;       // 131,072

    SvegaMaxPool2x2_kernel<<<blocks, 256, 0, stream>>>(X4, Y2, nthreads);
}